// Round 1
// baseline (1366.007 us; speedup 1.0000x reference)
//
#include <hip/hip_runtime.h>
#include <hip/hip_bf16.h>
#include <math.h>

// Problem constants
#define BB     4
#define CCH    256          // C
#define HH     128
#define WWID   128
#define NNPIX  (HH*WWID)    // 16384
#define NHEADS 8
#define NPTS   4
#define DHEAD  32           // C / HEADS
#define HPDIM  32           // HEADS*NPTS

// ---------------------------------------------------------------------------
// K1: V[b,n,c'] = sum_c x3[b,c,n] * Wv[c,c']   (output (B,N,C) row-major)
// Tile: 64 n x 256 c' per block, K chunks of 32. 256 threads, thread = (tn 0..15, tc 0..15),
// micro-tile 4n x 16c'.
// ---------------------------------------------------------------------------
__global__ __launch_bounds__(256) void k_vgemm(const float* __restrict__ x3,
                                               const float* __restrict__ Wv,
                                               float* __restrict__ V) {
  __shared__ float sA[32][64];    // [k][n]  8 KiB
  __shared__ float sB[32][256];   // [k][c'] 32 KiB
  const int b  = blockIdx.y;
  const int n0 = blockIdx.x * 64;
  const int t  = threadIdx.x;
  const int tn = t & 15, tc = t >> 4;
  float acc[4][16];
#pragma unroll
  for (int i = 0; i < 4; i++)
#pragma unroll
    for (int j = 0; j < 16; j++) acc[i][j] = 0.f;

  const float* xb = x3 + (size_t)b * CCH * NNPIX;
  for (int kc = 0; kc < 256; kc += 32) {
#pragma unroll
    for (int i = 0; i < 8; i++) {
      int k = i * 4 + (t >> 6);
      int n = t & 63;
      sA[k][n] = xb[(size_t)(kc + k) * NNPIX + n0 + n];
    }
#pragma unroll
    for (int k = 0; k < 32; k++) sB[k][t] = Wv[(kc + k) * 256 + t];
    __syncthreads();
#pragma unroll 8
    for (int k = 0; k < 32; k++) {
      float a[4];
      *(float4*)a = *(const float4*)&sA[k][tn * 4];
      float bv[16];
#pragma unroll
      for (int j = 0; j < 4; j++)
        *(float4*)&bv[j * 4] = *(const float4*)&sB[k][tc * 16 + j * 4];
#pragma unroll
      for (int i = 0; i < 4; i++)
#pragma unroll
        for (int j = 0; j < 16; j++) acc[i][j] = fmaf(a[i], bv[j], acc[i][j]);
    }
    __syncthreads();
  }
#pragma unroll
  for (int i = 0; i < 4; i++) {
    float* dst = V + ((size_t)b * NNPIX + n0 + tn * 4 + i) * 256 + tc * 16;
#pragma unroll
    for (int j = 0; j < 4; j++) *(float4*)(dst + j * 4) = *(float4*)&acc[i][j * 4];
  }
}

// ---------------------------------------------------------------------------
// K2: per (b, branch q, 16-n tile): logits (96 = 64 off + 32 aw), softmax over 32,
// bilinear sampling of V, weighted sum -> cat[(b*N+n)*512 + q*256 + c']
// ---------------------------------------------------------------------------
__global__ __launch_bounds__(256) void k_deform(
    const float* __restrict__ x1, const float* __restrict__ x2,
    const float* __restrict__ Woff1, const float* __restrict__ boff1,
    const float* __restrict__ Woff2, const float* __restrict__ boff2,
    const float* __restrict__ Waw1, const float* __restrict__ baw1,
    const float* __restrict__ Waw2, const float* __restrict__ baw2,
    const float* __restrict__ V, float* __restrict__ catb) {
  __shared__ float sX[256][16];   // x tile, [c][n]  16 KiB
  __shared__ float sL[96][16];    // logits [j][n]   6 KiB
  __shared__ float sAw[32][16];   // softmax'd aw [hp][n]
  __shared__ float sWx[16][32];   // bilinear frac [n][hp]
  __shared__ float sWy[16][32];
  __shared__ int   sX0[16][32];
  __shared__ int   sY0[16][32];

  const int q  = blockIdx.z;
  const int b  = blockIdx.y;
  const int n0 = blockIdx.x * 16;
  const int t  = threadIdx.x;

  const float* x    = q ? x2 : x1;
  const float* Woff = q ? Woff2 : Woff1;
  const float* boff = q ? boff2 : boff1;
  const float* Waw  = q ? Waw2 : Waw1;
  const float* baw  = q ? baw2 : baw1;

  // stage x tile: 256 c x 16 n
#pragma unroll
  for (int i = 0; i < 16; i++) {
    int c = i * 16 + (t >> 4);
    int n = t & 15;
    sX[c][n] = x[((size_t)b * CCH + c) * NNPIX + n0 + n];
  }
  __syncthreads();

  // logits: thread -> (n_local = t>>4, jg = t&15), 6 outputs j = k*16+jg
  {
    const int nl = t >> 4, jg = t & 15;
    float acc[6] = {0.f, 0.f, 0.f, 0.f, 0.f, 0.f};
#pragma unroll 4
    for (int c = 0; c < 256; c++) {
      float xv = sX[c][nl];
      acc[0] = fmaf(xv, Woff[c * 64 + jg], acc[0]);
      acc[1] = fmaf(xv, Woff[c * 64 + 16 + jg], acc[1]);
      acc[2] = fmaf(xv, Woff[c * 64 + 32 + jg], acc[2]);
      acc[3] = fmaf(xv, Woff[c * 64 + 48 + jg], acc[3]);
      acc[4] = fmaf(xv, Waw[c * 32 + jg], acc[4]);
      acc[5] = fmaf(xv, Waw[c * 32 + 16 + jg], acc[5]);
    }
    sL[jg][nl]      = acc[0] + boff[jg];
    sL[16 + jg][nl] = acc[1] + boff[16 + jg];
    sL[32 + jg][nl] = acc[2] + boff[32 + jg];
    sL[48 + jg][nl] = acc[3] + boff[48 + jg];
    sL[64 + jg][nl] = acc[4] + baw[jg];
    sL[80 + jg][nl] = acc[5] + baw[16 + jg];
  }
  __syncthreads();

  // bilinear params for 512 (n,hp) pairs
  for (int pr = t; pr < 512; pr += 256) {
    int n = pr >> 5, hp = pr & 31;
    int ng = n0 + n;
    int wimg = ng & (WWID - 1);
    int himg = ng >> 7;
    float offx = sL[hp * 2][n];
    float offy = sL[hp * 2 + 1][n];
    float refx = (wimg + 0.5f) * (1.0f / WWID);
    float refy = (himg + 0.5f) * (1.0f / HH);
    float gx = 2.0f * (refx + offx) - 1.0f;
    float gy = 2.0f * (refy + offy) - 1.0f;
    float ix = ((gx + 1.0f) * WWID - 1.0f) * 0.5f;
    float iy = ((gy + 1.0f) * HH - 1.0f) * 0.5f;
    float x0f = floorf(ix), y0f = floorf(iy);
    sWx[n][hp] = ix - x0f;
    sWy[n][hp] = iy - y0f;
    sX0[n][hp] = (int)x0f;
    sY0[n][hp] = (int)y0f;
  }
  // softmax over 32 aw logits (rows 64..95)
  if (t < 16) {
    float mx = -1e30f;
#pragma unroll
    for (int j = 0; j < 32; j++) mx = fmaxf(mx, sL[64 + j][t]);
    float s = 0.f;
#pragma unroll
    for (int j = 0; j < 32; j++) {
      float e = __expf(sL[64 + j][t] - mx);
      sAw[j][t] = e;
      s += e;
    }
    float inv = 1.0f / s;
#pragma unroll
    for (int j = 0; j < 32; j++) sAw[j][t] *= inv;
  }
  __syncthreads();

  // sampling: thread = (h = t>>5, dd = t&31); loop over 16 n, 4 p, 4 corners
  const int dd = t & 31;
  const int h  = t >> 5;
  const float* Vb = V + (size_t)b * NNPIX * CCH + h * 32 + dd;
  float* outp = catb + ((size_t)(b * (size_t)NNPIX + n0)) * 512 + q * 256 + h * 32 + dd;
  for (int n = 0; n < 16; n++) {
    float acc = 0.f;
#pragma unroll
    for (int p = 0; p < 4; p++) {
      const int hp = h * 4 + p;
      const int xx0 = sX0[n][hp];
      const int yy0 = sY0[n][hp];
      const float wx = sWx[n][hp];
      const float wy = sWy[n][hp];
      const float awv = sAw[hp][n];
      float s = 0.f;
      const bool vx0 = (unsigned)xx0 < (unsigned)WWID;
      const bool vx1 = (unsigned)(xx0 + 1) < (unsigned)WWID;
      if ((unsigned)yy0 < (unsigned)HH) {
        const float* r0 = Vb + (size_t)(yy0 * WWID) * 256;
        if (vx0) s += (1.f - wx) * (1.f - wy) * r0[(size_t)xx0 * 256];
        if (vx1) s += wx * (1.f - wy) * r0[(size_t)(xx0 + 1) * 256];
      }
      if ((unsigned)(yy0 + 1) < (unsigned)HH) {
        const float* r1 = Vb + (size_t)((yy0 + 1) * WWID) * 256;
        if (vx0) s += (1.f - wx) * wy * r1[(size_t)xx0 * 256];
        if (vx1) s += wx * wy * r1[(size_t)(xx0 + 1) * 256];
      }
      acc += awv * s;
    }
    outp[(size_t)n * 512] = acc;
  }
}

// ---------------------------------------------------------------------------
// K3: out[b,c,n] = bout[c] + sum_k cat[b,n,k] * Wout[k,c]  (K=512)
// Same tiling as K1; A needs transpose staging (row-major (n,k)).
// ---------------------------------------------------------------------------
__global__ __launch_bounds__(256) void k_out(const float* __restrict__ catb,
                                             const float* __restrict__ Wout,
                                             const float* __restrict__ bout,
                                             float* __restrict__ out) {
  __shared__ float sA[32][68];    // [k][n] padded (+4 floats: 16B-aligned rows)
  __shared__ float sB[32][256];   // [k][c]
  const int b  = blockIdx.y;
  const int n0 = blockIdx.x * 64;
  const int t  = threadIdx.x;
  const int tn = t & 15, tc = t >> 4;
  float acc[4][16];
#pragma unroll
  for (int i = 0; i < 4; i++)
#pragma unroll
    for (int j = 0; j < 16; j++) acc[i][j] = 0.f;

  const float* Ab = catb + (size_t)b * NNPIX * 512;
  for (int kc = 0; kc < 512; kc += 32) {
#pragma unroll
    for (int i = 0; i < 8; i++) {
      int idx = i * 256 + t;
      int n = idx >> 5;
      int k = idx & 31;
      sA[k][n] = Ab[(size_t)(n0 + n) * 512 + kc + k];
    }
#pragma unroll
    for (int k = 0; k < 32; k++) sB[k][t] = Wout[(kc + k) * 256 + t];
    __syncthreads();
#pragma unroll 8
    for (int k = 0; k < 32; k++) {
      float a[4];
      *(float4*)a = *(const float4*)&sA[k][tn * 4];
      float bv[16];
#pragma unroll
      for (int j = 0; j < 4; j++)
        *(float4*)&bv[j * 4] = *(const float4*)&sB[k][tc * 16 + j * 4];
#pragma unroll
      for (int i = 0; i < 4; i++)
#pragma unroll
        for (int j = 0; j < 16; j++) acc[i][j] = fmaf(a[i], bv[j], acc[i][j]);
    }
    __syncthreads();
  }
#pragma unroll
  for (int j = 0; j < 16; j++) {
    int c = tc * 16 + j;
    float bo = bout[c];
    float4 v = make_float4(acc[0][j] + bo, acc[1][j] + bo, acc[2][j] + bo, acc[3][j] + bo);
    *(float4*)(out + ((size_t)b * CCH + c) * NNPIX + n0 + tn * 4) = v;
  }
}

// ---------------------------------------------------------------------------
extern "C" void kernel_launch(void* const* d_in, const int* in_sizes, int n_in,
                              void* d_out, int out_size, void* d_ws, size_t ws_size,
                              hipStream_t stream) {
  const float* x1    = (const float*)d_in[0];
  const float* x2    = (const float*)d_in[1];
  const float* x3    = (const float*)d_in[2];
  const float* Wv    = (const float*)d_in[3];
  const float* Woff1 = (const float*)d_in[4];
  const float* boff1 = (const float*)d_in[5];
  const float* Woff2 = (const float*)d_in[6];
  const float* boff2 = (const float*)d_in[7];
  const float* Waw1  = (const float*)d_in[8];
  const float* baw1  = (const float*)d_in[9];
  const float* Waw2  = (const float*)d_in[10];
  const float* baw2  = (const float*)d_in[11];
  const float* Wout  = (const float*)d_in[12];
  const float* bout  = (const float*)d_in[13];
  float* out = (float*)d_out;

  // workspace: V (B*N*C f32 = 64 MiB) | cat (B*N*512 f32 = 128 MiB)
  float* V   = (float*)d_ws;
  float* cat = V + (size_t)BB * NNPIX * CCH;

  k_vgemm<<<dim3(NNPIX / 64, BB), 256, 0, stream>>>(x3, Wv, V);
  k_deform<<<dim3(NNPIX / 16, BB, 2), 256, 0, stream>>>(x1, x2, Woff1, boff1, Woff2, boff2,
                                                        Waw1, baw1, Waw2, baw2, V, cat);
  k_out<<<dim3(NNPIX / 64, BB), 256, 0, stream>>>(cat, Wout, bout, out);
}

// Round 2
// 877.843 us; speedup vs baseline: 1.5561x; 1.5561x over previous
//
#include <hip/hip_runtime.h>
#include <hip/hip_bf16.h>
#include <math.h>

// Problem constants
#define BB     4
#define CCH    256          // C
#define HH     128
#define WWID   128
#define NNPIX  (HH*WWID)    // 16384
#define NHEADS 8
#define NPTS   4
#define DHEAD  32           // C / HEADS
#define HPDIM  32           // HEADS*NPTS

// ---------------------------------------------------------------------------
// K1: V[b,n,c'] = sum_c x3[b,c,n] * Wv[c,c']   (output (B,N,C) row-major)
// ---------------------------------------------------------------------------
__global__ __launch_bounds__(256) void k_vgemm(const float* __restrict__ x3,
                                               const float* __restrict__ Wv,
                                               float* __restrict__ V) {
  __shared__ float sA[32][64];    // [k][n]  8 KiB
  __shared__ float sB[32][256];   // [k][c'] 32 KiB
  const int b  = blockIdx.y;
  const int n0 = blockIdx.x * 64;
  const int t  = threadIdx.x;
  const int tn = t & 15, tc = t >> 4;
  float acc[4][16];
#pragma unroll
  for (int i = 0; i < 4; i++)
#pragma unroll
    for (int j = 0; j < 16; j++) acc[i][j] = 0.f;

  const float* xb = x3 + (size_t)b * CCH * NNPIX;
  for (int kc = 0; kc < 256; kc += 32) {
#pragma unroll
    for (int i = 0; i < 8; i++) {
      int k = i * 4 + (t >> 6);
      int n = t & 63;
      sA[k][n] = xb[(size_t)(kc + k) * NNPIX + n0 + n];
    }
#pragma unroll
    for (int k = 0; k < 32; k++) sB[k][t] = Wv[(kc + k) * 256 + t];
    __syncthreads();
#pragma unroll 8
    for (int k = 0; k < 32; k++) {
      float a[4];
      *(float4*)a = *(const float4*)&sA[k][tn * 4];
      float bv[16];
#pragma unroll
      for (int j = 0; j < 4; j++)
        *(float4*)&bv[j * 4] = *(const float4*)&sB[k][tc * 16 + j * 4];
#pragma unroll
      for (int i = 0; i < 4; i++)
#pragma unroll
        for (int j = 0; j < 16; j++) acc[i][j] = fmaf(a[i], bv[j], acc[i][j]);
    }
    __syncthreads();
  }
#pragma unroll
  for (int i = 0; i < 4; i++) {
    float* dst = V + ((size_t)b * NNPIX + n0 + tn * 4 + i) * 256 + tc * 16;
#pragma unroll
    for (int j = 0; j < 4; j++) *(float4*)(dst + j * 4) = *(float4*)&acc[i][j * 4];
  }
}

// ---------------------------------------------------------------------------
// K2: per (b, branch q, 32-n tile): logits (96), softmax over 32, bilinear
// sampling of V, weighted sum -> cat[(b*N+n)*512 + q*256 + c']
// Phases: stage x [n][c] -> logits (vectorized weights, 2 n/thread) ->
//         params+softmax -> float4 branchless gather
// ---------------------------------------------------------------------------
struct ParamS {
  float sWx[32][32];
  float sWy[32][32];
  float sAw[32][32];
  int   sXY[32][32];
};
union SMemU {
  float sX[32][260];   // 33,280 B  (row stride 260: 1040 B, 16B-aligned)
  ParamS p;            // 16,384 B  (reuses the x region after logits)
};

__global__ __launch_bounds__(256) void k_deform(
    const float* __restrict__ x1, const float* __restrict__ x2,
    const float* __restrict__ Woff1, const float* __restrict__ boff1,
    const float* __restrict__ Woff2, const float* __restrict__ boff2,
    const float* __restrict__ Waw1, const float* __restrict__ baw1,
    const float* __restrict__ Waw2, const float* __restrict__ baw2,
    const float* __restrict__ V, float* __restrict__ catb) {
  __shared__ SMemU sm;
  __shared__ float sL[96][33];   // logits [j][n], padded

  const int q  = blockIdx.z;
  const int b  = blockIdx.y;
  const int n0 = blockIdx.x * 32;
  const int t  = threadIdx.x;

  const float* x    = q ? x2 : x1;
  const float* Woff = q ? Woff2 : Woff1;
  const float* boff = q ? boff2 : boff1;
  const float* Waw  = q ? Waw2 : Waw1;
  const float* baw  = q ? baw2 : baw1;

  // ---- stage x tile: 256 c x 32 n, stored [n][c] ----
#pragma unroll
  for (int i = 0; i < 32; i++) {
    int c = i * 8 + (t >> 5);
    int n = t & 31;
    sm.sX[n][c] = x[((size_t)b * CCH + c) * NNPIX + n0 + n];
  }
  __syncthreads();

  // ---- logits: thread (nl = t>>4, jg = t&15); 2 n-rows per thread ----
  {
    const int jg = t & 15, nl = t >> 4;
    const float* wop = Woff + jg * 4;
    const float* wap = Waw + jg * 2;
    float aO0[4] = {0.f, 0.f, 0.f, 0.f};
    float aO1[4] = {0.f, 0.f, 0.f, 0.f};
    float aA0[2] = {0.f, 0.f};
    float aA1[2] = {0.f, 0.f};
    for (int c = 0; c < 256; c += 4) {
      float4 xa = *(const float4*)&sm.sX[nl][c];
      float4 xb4 = *(const float4*)&sm.sX[nl + 16][c];
#pragma unroll
      for (int cc = 0; cc < 4; cc++) {
        const float4 wo = *(const float4*)&wop[(c + cc) * 64];
        const float2 wa = *(const float2*)&wap[(c + cc) * 32];
        const float xv0 = ((const float*)&xa)[cc];
        const float xv1 = ((const float*)&xb4)[cc];
        aO0[0] = fmaf(xv0, wo.x, aO0[0]);
        aO0[1] = fmaf(xv0, wo.y, aO0[1]);
        aO0[2] = fmaf(xv0, wo.z, aO0[2]);
        aO0[3] = fmaf(xv0, wo.w, aO0[3]);
        aO1[0] = fmaf(xv1, wo.x, aO1[0]);
        aO1[1] = fmaf(xv1, wo.y, aO1[1]);
        aO1[2] = fmaf(xv1, wo.z, aO1[2]);
        aO1[3] = fmaf(xv1, wo.w, aO1[3]);
        aA0[0] = fmaf(xv0, wa.x, aA0[0]);
        aA0[1] = fmaf(xv0, wa.y, aA0[1]);
        aA1[0] = fmaf(xv1, wa.x, aA1[0]);
        aA1[1] = fmaf(xv1, wa.y, aA1[1]);
      }
    }
#pragma unroll
    for (int k = 0; k < 4; k++) {
      const float bo = boff[jg * 4 + k];
      sL[jg * 4 + k][nl]      = aO0[k] + bo;
      sL[jg * 4 + k][nl + 16] = aO1[k] + bo;
    }
#pragma unroll
    for (int k = 0; k < 2; k++) {
      const float ba = baw[jg * 2 + k];
      sL[64 + jg * 2 + k][nl]      = aA0[k] + ba;
      sL[64 + jg * 2 + k][nl + 16] = aA1[k] + ba;
    }
  }
  __syncthreads();

  // ---- bilinear params for 1024 (n,hp) pairs (overwrites x region) ----
#pragma unroll
  for (int it = 0; it < 4; it++) {
    int pr = it * 256 + t;
    int n = pr >> 5, hp = pr & 31;
    int ng = n0 + n;
    int wimg = ng & (WWID - 1);
    int himg = ng >> 7;
    float offx = sL[hp * 2][n];
    float offy = sL[hp * 2 + 1][n];
    float refx = (wimg + 0.5f) * (1.0f / WWID);
    float refy = (himg + 0.5f) * (1.0f / HH);
    float gx = 2.0f * (refx + offx) - 1.0f;
    float gy = 2.0f * (refy + offy) - 1.0f;
    float ix = ((gx + 1.0f) * WWID - 1.0f) * 0.5f;
    float iy = ((gy + 1.0f) * HH - 1.0f) * 0.5f;
    float x0f = floorf(ix), y0f = floorf(iy);
    int xi = (int)x0f, yi = (int)y0f;
    sm.p.sWx[n][hp] = ix - x0f;
    sm.p.sWy[n][hp] = iy - y0f;
    sm.p.sXY[n][hp] = (xi & 0xffff) | (yi << 16);
  }
  // softmax over 32 aw logits (rows 64..95), one thread per n
  if (t < 32) {
    float mx = -1e30f;
#pragma unroll
    for (int j = 0; j < 32; j++) mx = fmaxf(mx, sL[64 + j][t]);
    float s = 0.f;
    float e[32];
#pragma unroll
    for (int j = 0; j < 32; j++) {
      e[j] = __expf(sL[64 + j][t] - mx);
      s += e[j];
    }
    float inv = 1.0f / s;
#pragma unroll
    for (int j = 0; j < 32; j++) sm.p.sAw[t][j] = e[j] * inv;
  }
  __syncthreads();

  // ---- sampling: thread = (wv = t>>6, h = (t>>3)&7, d4 = t&7) ----
  const int d4 = (t & 7) * 4;
  const int h  = (t >> 3) & 7;
  const int wv = t >> 6;
  const float* Vb = V + (size_t)b * NNPIX * CCH + h * 32 + d4;
  float* outp = catb + ((size_t)b * NNPIX + n0) * 512 + q * 256 + h * 32 + d4;
#pragma unroll 2
  for (int ni = 0; ni < 8; ni++) {
    const int n = wv * 8 + ni;
    float a0 = 0.f, a1 = 0.f, a2 = 0.f, a3 = 0.f;
#pragma unroll
    for (int p = 0; p < 4; p++) {
      const int hp = h * 4 + p;
      const int xy = sm.p.sXY[n][hp];
      const int x0 = (int)(short)(xy & 0xffff);
      const int y0 = xy >> 16;
      const float wx = sm.p.sWx[n][hp];
      const float wy = sm.p.sWy[n][hp];
      const float aw = sm.p.sAw[n][hp];
      const float axw = 1.f - wx, ayw = 1.f - wy;
      const bool vx0 = (unsigned)x0 < (unsigned)WWID;
      const bool vx1 = (unsigned)(x0 + 1) < (unsigned)WWID;
      const bool vy0 = (unsigned)y0 < (unsigned)HH;
      const bool vy1 = (unsigned)(y0 + 1) < (unsigned)HH;
      const float w00 = (vx0 && vy0) ? axw * ayw * aw : 0.f;
      const float w01 = (vx1 && vy0) ? wx * ayw * aw : 0.f;
      const float w10 = (vx0 && vy1) ? axw * wy * aw : 0.f;
      const float w11 = (vx1 && vy1) ? wx * wy * aw : 0.f;
      const int xc0 = min(max(x0, 0), WWID - 1);
      const int xc1 = min(max(x0 + 1, 0), WWID - 1);
      const int yr0 = min(max(y0, 0), HH - 1) << 7;
      const int yr1 = min(max(y0 + 1, 0), HH - 1) << 7;
      const float4 v00 = *(const float4*)(Vb + ((size_t)(yr0 + xc0) << 8));
      const float4 v01 = *(const float4*)(Vb + ((size_t)(yr0 + xc1) << 8));
      const float4 v10 = *(const float4*)(Vb + ((size_t)(yr1 + xc0) << 8));
      const float4 v11 = *(const float4*)(Vb + ((size_t)(yr1 + xc1) << 8));
      a0 = fmaf(w00, v00.x, fmaf(w01, v01.x, fmaf(w10, v10.x, fmaf(w11, v11.x, a0))));
      a1 = fmaf(w00, v00.y, fmaf(w01, v01.y, fmaf(w10, v10.y, fmaf(w11, v11.y, a1))));
      a2 = fmaf(w00, v00.z, fmaf(w01, v01.z, fmaf(w10, v10.z, fmaf(w11, v11.z, a2))));
      a3 = fmaf(w00, v00.w, fmaf(w01, v01.w, fmaf(w10, v10.w, fmaf(w11, v11.w, a3))));
    }
    *(float4*)(outp + (size_t)n * 512) = make_float4(a0, a1, a2, a3);
  }
}

// ---------------------------------------------------------------------------
// K3: out[b,c,n] = bout[c] + sum_k cat[b,n,k] * Wout[k,c]  (K=512)
// ---------------------------------------------------------------------------
__global__ __launch_bounds__(256) void k_out(const float* __restrict__ catb,
                                             const float* __restrict__ Wout,
                                             const float* __restrict__ bout,
                                             float* __restrict__ out) {
  __shared__ float sA[32][68];    // [k][n] padded
  __shared__ float sB[32][256];   // [k][c]
  const int b  = blockIdx.y;
  const int n0 = blockIdx.x * 64;
  const int t  = threadIdx.x;
  const int tn = t & 15, tc = t >> 4;
  float acc[4][16];
#pragma unroll
  for (int i = 0; i < 4; i++)
#pragma unroll
    for (int j = 0; j < 16; j++) acc[i][j] = 0.f;

  const float* Ab = catb + (size_t)b * NNPIX * 512;
  for (int kc = 0; kc < 512; kc += 32) {
#pragma unroll
    for (int i = 0; i < 8; i++) {
      int idx = i * 256 + t;
      int n = idx >> 5;
      int k = idx & 31;
      sA[k][n] = Ab[(size_t)(n0 + n) * 512 + kc + k];
    }
#pragma unroll
    for (int k = 0; k < 32; k++) sB[k][t] = Wout[(kc + k) * 256 + t];
    __syncthreads();
#pragma unroll 8
    for (int k = 0; k < 32; k++) {
      float a[4];
      *(float4*)a = *(const float4*)&sA[k][tn * 4];
      float bv[16];
#pragma unroll
      for (int j = 0; j < 4; j++)
        *(float4*)&bv[j * 4] = *(const float4*)&sB[k][tc * 16 + j * 4];
#pragma unroll
      for (int i = 0; i < 4; i++)
#pragma unroll
        for (int j = 0; j < 16; j++) acc[i][j] = fmaf(a[i], bv[j], acc[i][j]);
    }
    __syncthreads();
  }
#pragma unroll
  for (int j = 0; j < 16; j++) {
    int c = tc * 16 + j;
    float bo = bout[c];
    float4 v = make_float4(acc[0][j] + bo, acc[1][j] + bo, acc[2][j] + bo, acc[3][j] + bo);
    *(float4*)(out + ((size_t)b * CCH + c) * NNPIX + n0 + tn * 4) = v;
  }
}

// ---------------------------------------------------------------------------
extern "C" void kernel_launch(void* const* d_in, const int* in_sizes, int n_in,
                              void* d_out, int out_size, void* d_ws, size_t ws_size,
                              hipStream_t stream) {
  const float* x1    = (const float*)d_in[0];
  const float* x2    = (const float*)d_in[1];
  const float* x3    = (const float*)d_in[2];
  const float* Wv    = (const float*)d_in[3];
  const float* Woff1 = (const float*)d_in[4];
  const float* boff1 = (const float*)d_in[5];
  const float* Woff2 = (const float*)d_in[6];
  const float* boff2 = (const float*)d_in[7];
  const float* Waw1  = (const float*)d_in[8];
  const float* baw1  = (const float*)d_in[9];
  const float* Waw2  = (const float*)d_in[10];
  const float* baw2  = (const float*)d_in[11];
  const float* Wout  = (const float*)d_in[12];
  const float* bout  = (const float*)d_in[13];
  float* out = (float*)d_out;

  // workspace: V (B*N*C f32 = 64 MiB) | cat (B*N*512 f32 = 128 MiB)
  float* V   = (float*)d_ws;
  float* cat = V + (size_t)BB * NNPIX * CCH;

  k_vgemm<<<dim3(NNPIX / 64, BB), 256, 0, stream>>>(x3, Wv, V);
  k_deform<<<dim3(NNPIX / 32, BB, 2), 256, 0, stream>>>(x1, x2, Woff1, boff1, Woff2, boff2,
                                                        Waw1, baw1, Waw2, baw2, V, cat);
  k_out<<<dim3(NNPIX / 64, BB), 256, 0, stream>>>(cat, Wout, bout, out);
}